// Round 8
// baseline (236.874 us; speedup 1.0000x reference)
//
#include <hip/hip_runtime.h>

#define IMG   1024
#define BH    16               // output rows per band; 64 bands x 16 imgs = 1024 wgs = 4/CU
#define STEPS (BH + 12)        // 28: pipeline lag 2+2+2 each side
#define LW    1032             // LDS row floats: 4 zero-pad | 1024 | 4 zero-pad
#define PADL  4

typedef __attribute__((address_space(1))) const void gv_t;
typedef __attribute__((address_space(3))) void lv_t;

// Fused 3-iteration Perona-Malik row-sweep.
// LDS holds 3-row rings of field0(input)/field1/field2; flux lives in per-lane
// register rings (6-wide redundant windows, no cross-lane exchange per stage).
// 2 barriers per step. Row/step predicates write ZEROS for out-of-range rows,
// reproducing the conv SAME zero-pad; LDS pad cols do the same horizontally.
__global__ __launch_bounds__(256, 4)
void pm_fused3(const float* __restrict__ in, float* __restrict__ out) {
    __shared__ __align__(16) float S[9 * LW];  // rows 0-2: f0 ring, 3-5: f1, 6-8: f2

    const int tid = threadIdx.x;
    const int c0  = tid << 2;                  // owned cols c0..c0+3
    const int Y0  = blockIdx.x * BH;
    const size_t base = (size_t)blockIdx.y << 20;
    const float* I = in + base;
    float* O = out + base;
    const bool le = (c0 == 0), re = (c0 == IMG - 4);

    // zero the pad columns of all 9 LDS rows (never rewritten afterwards)
    if (tid < 72) {
        const int r = tid >> 3, j = tid & 7;
        S[r * LW + ((j < 4) ? j : (1024 + j))] = 0.f;
    }

    // ring row-start offsets (floats), newest..oldest
    int i0 = 0,    i1 = LW,     i2 = 2 * LW;   // field0 (input)
    int u0 = 3*LW, u1 = 4 * LW, u2 = 5 * LW;   // field1
    int v0 = 6*LW, v1 = 7 * LW, v2 = 8 * LW;   // field2

    const int wb = (tid >> 6) << 8;            // wave-uniform col base (0/256/512/768)

    // prologue: input row Y0-6 -> slot i0
    {
        const int row = Y0 - 6;                // always < IMG
        if (row >= 0)
            __builtin_amdgcn_global_load_lds((gv_t*)(I + ((size_t)row << 10) + c0),
                                             (lv_t*)(S + i0 + PADL + wb), 16, 0, 0);
        else
            *(float4*)&S[i0 + PADL + c0] = make_float4(0.f, 0.f, 0.f, 0.f);
    }
    __syncthreads();

    const int vbw = PADL + c0 - 2;             // 8-wide window base (8B-aligned)

    // flux register rings per stage (rows m-1, m-2)
    float a1x[6],a1y[6],a2x[6],a2y[6];
    float b1x[6],b1y[6],b2x[6],b2y[6];
    float c1x[6],c1y[6],c2x[6],c2y[6];
    #pragma unroll
    for (int j = 0; j < 6; ++j) {
        a1x[j]=a1y[j]=a2x[j]=a2y[j]=0.f;
        b1x[j]=b1y[j]=b2x[j]=b2y[j]=0.f;
        c1x[j]=c1y[j]=c2x[j]=c2y[j]=0.f;
    }

    auto rd8 = [&](int ro, float* w) {        // 8-wide window of one LDS row
        float2 t0 = *(const float2*)&S[ro + vbw];
        float4 t1 = *(const float4*)&S[ro + vbw + 2];
        float2 t2 = *(const float2*)&S[ro + vbw + 6];
        w[0]=t0.x; w[1]=t0.y; w[2]=t1.x; w[3]=t1.y;
        w[4]=t1.z; w[5]=t1.w; w[6]=t2.x; w[7]=t2.y;
    };

    auto flux6 = [&](const float* um, const float* uc, const float* up, bool valid,
                     float* fx, float* fy) {
        if (valid) {
            float s[8], d[8];
            #pragma unroll
            for (int j = 0; j < 8; ++j) { s[j]=fmaf(2.f,uc[j],um[j]+up[j]); d[j]=up[j]-um[j]; }
            #pragma unroll
            for (int i = 0; i < 6; ++i) {
                const float GX  = s[i+2] - s[i];                    // 8*grad_x
                const float GY  = fmaf(2.f, d[i+1], d[i] + d[i+2]); // 8*grad_y
                const float m2  = fmaf(GY, GY, GX * GX);
                const float mag = fmaf(m2, 0.015625f, 1e-8f);       // g^2 + eps
                const float den = fmaf(mag, 400.f, 1.f);            // 1 + g^2/k^2
                const float c   = __builtin_amdgcn_rcpf(den);
                fx[i] = c * GX; fy[i] = c * GY;                     // 8*flux
            }
            if (le) { fx[0]=0.f; fy[0]=0.f; }   // flux zero-padded by 2nd conv
            if (re) { fx[5]=0.f; fy[5]=0.f; }
        } else {
            #pragma unroll
            for (int i = 0; i < 6; ++i) { fx[i]=0.f; fy[i]=0.f; }
        }
    };

    auto div4 = [&](const float* f2x_, const float* f1x_, const float* fNx_,
                    const float* f2y_, const float* f1y_, const float* fNy_,
                    const float* ctr, bool wr, float* o) {
        float Sx[6], Dy[6];
        #pragma unroll
        for (int j = 0; j < 6; ++j) {
            Sx[j] = fmaf(2.f, f1x_[j], f2x_[j] + fNx_[j]);
            Dy[j] = fNy_[j] - f2y_[j];
        }
        #pragma unroll
        for (int i = 0; i < 4; ++i) {
            const float DX = Sx[i+2] - Sx[i];
            const float DY = fmaf(2.f, Dy[i+1], Dy[i] + Dy[i+2]);
            o[i] = wr ? fmaf(DX + DY, 0.00390625f, ctr[i+2]) : 0.f;  // in + dt*div/64
        }
    };

    #pragma unroll 2
    for (int k = 0; k < STEPS; ++k) {
        // ================= phase A : stage 1 =================
        // input rows in ring: i0 = Y0-6+k (newest), i1, i2 older
        float um[8], uc[8], up[8];
        rd8(i2, um); rd8(i1, uc); rd8(i0, up);
        float aNx[6], aNy[6];
        const int yf1 = Y0 - 7 + k;                        // flux1 row
        flux6(um, uc, up, (unsigned)yf1 < IMG, aNx, aNy);
        const int L1 = Y0 - 8 + k;                         // field1 row
        float o1[4];
        div4(a2x,a1x,aNx, a2y,a1y,aNy, um, (k >= 4) && ((unsigned)L1 < IMG), o1);
        { int t=u2; u2=u1; u1=u0; u0=t; }                  // rotate field1 ring
        *(float4*)&S[u0 + PADL + c0] = make_float4(o1[0],o1[1],o1[2],o1[3]);
        #pragma unroll
        for (int j=0;j<6;++j){ a2x[j]=a1x[j]; a2y[j]=a1y[j]; a1x[j]=aNx[j]; a1y[j]=aNy[j]; }
        __syncthreads();   // bar1: field1 row L1 visible; input WAR protected

        // ================= phase B : prefetch + stage 2 =================
        if (k < STEPS - 1) {
            { int t=i2; i2=i1; i1=i0; i0=t; }              // rotate field0 ring
            const int row = Y0 - 5 + k;                    // next input row
            if ((unsigned)row < IMG)
                __builtin_amdgcn_global_load_lds((gv_t*)(I + ((size_t)row << 10) + c0),
                                                 (lv_t*)(S + i0 + PADL + wb), 16, 0, 0);
            else
                *(float4*)&S[i0 + PADL + c0] = make_float4(0.f, 0.f, 0.f, 0.f);
        }
        float vm[8], vc[8], vp[8];
        rd8(u2, vm); rd8(u1, vc); rd8(u0, vp);             // field1 rows L1-2..L1
        float bNx[6], bNy[6];
        flux6(vm, vc, vp, (unsigned)(L1 - 1) < IMG, bNx, bNy);
        const int h = L1 - 2;                              // field2 row
        float o2[4];
        div4(b2x,b1x,bNx, b2y,b1y,bNy, vm, (k >= 8) && ((unsigned)h < IMG), o2);
        { int t=v2; v2=v1; v1=v0; v0=t; }                  // rotate field2 ring
        *(float4*)&S[v0 + PADL + c0] = make_float4(o2[0],o2[1],o2[2],o2[3]);
        #pragma unroll
        for (int j=0;j<6;++j){ b2x[j]=b1x[j]; b2y[j]=b1y[j]; b1x[j]=bNx[j]; b1y[j]=bNy[j]; }
        __syncthreads();   // bar2: field2 row h visible; prefetch drained

        // ================= phase C : stage 3 =================
        float wm[8], wc[8], wp[8];
        rd8(v2, wm); rd8(v1, wc); rd8(v0, wp);             // field2 rows h-2..h
        float cNx[6], cNy[6];
        flux6(wm, wc, wp, (unsigned)(h - 1) < IMG, cNx, cNy);
        float o3[4];
        div4(c2x,c1x,cNx, c2y,c1y,cNy, wm, true, o3);
        if (k >= 12) {                                     // y = Y0..Y0+BH-1 exactly
            const int y = Y0 + (k - 12);
            *(float4*)(O + ((size_t)y << 10) + c0) = make_float4(o3[0],o3[1],o3[2],o3[3]);
        }
        #pragma unroll
        for (int j=0;j<6;++j){ c2x[j]=c1x[j]; c2y[j]=c1y[j]; c1x[j]=cNx[j]; c1y[j]=cNy[j]; }
    }
}

extern "C" void kernel_launch(void* const* d_in, const int* in_sizes, int n_in,
                              void* d_out, int out_size, void* d_ws, size_t ws_size,
                              hipStream_t stream) {
    const float* img = (const float*)d_in[0];
    float* out = (float*)d_out;
    const int N = in_sizes[0] / (IMG * IMG);

    dim3 grid(IMG / BH, N);   // 64 x 16 = 1024 workgroups = 4 blocks/CU exactly
    dim3 block(256);
    pm_fused3<<<grid, block, 0, stream>>>(img, out);
}